// Round 6
// baseline (395.177 us; speedup 1.0000x reference)
//
#include <hip/hip_runtime.h>
#include <hip/hip_bf16.h>
#include <math.h>

#define NB 4
#define LB 16384
#define CB 256
#define HB 8
#define DB 32
#define NLB (NB * LB)
#define SPLITS 32
#define SPLIT_ROWS (LB / SPLITS)  // 512

typedef unsigned short ushort_t;
typedef __attribute__((ext_vector_type(8))) short bf16x8;
typedef __attribute__((ext_vector_type(4))) float f32x4;

__device__ __forceinline__ ushort_t f2b(float f) {
  union { __hip_bfloat16 h; ushort_t u; } cv;
  cv.h = __float2bfloat16(f);
  return cv.u;
}
__device__ __forceinline__ float b2f(ushort_t u) {
  union { __hip_bfloat16 h; ushort_t u; } cv;
  cv.u = u;
  return __bfloat162float(cv.h);
}

__device__ __forceinline__ void gload16(const void* g, void* l) {
  __builtin_amdgcn_global_load_lds(
      (const __attribute__((address_space(1))) void*)g,
      (__attribute__((address_space(3))) void*)l, 16, 0, 0);
}

// ---------------------------------------------------------------------------
// MFMA GEMM core v3: 128x256 tile, 512 threads (8 waves: wr=w>>2, wc=w&3),
// BK=64. B (and A when bf16) staged via width-16 global_load_lds into LINEAR
// LDS with INVERSE-swizzled global source (rule #21): LDS slot (r,s') holds
// global slot (r, s'^(r&7)); ds_read applies the same XOR -> conflict-free
// (round-5 verified: SQ_LDS_BANK_CONFLICT = 0). AF32 path keeps reg-staging
// with f32->bf16 convert (same LDS invariant).
// Fragments (round-4/5 verified): A lane lr=row, q=k-slot; B lane lr=col,
// q=k-slot; C row=4q+reg, col=lr.
// ---------------------------------------------------------------------------
template <int AF32>
__device__ __forceinline__ void gemm_core3(const void* A, int strideA,
                                           const ushort_t* __restrict__ WT,
                                           int strideB, short* As, short* Bs,
                                           f32x4 acc[4][4], int nk) {
  const int t = threadIdx.x;
  const int lane = t & 63;
  const int w = t >> 6, wr = w >> 2, wc = w & 3;
  const int q = lane >> 4, lr = lane & 15;
  for (int ks = 0; ks < nk; ++ks) {
    const int k0 = ks * 64;
    __syncthreads();
    if (AF32) {
      // reg-staged A (fp32 -> bf16), 2 slots/thread
      #pragma unroll
      for (int rep = 0; rep < 2; ++rep) {
        int si = t + 512 * rep;
        int r = si >> 3, s = si & 7;
        int dst = r * 64 + ((s ^ (r & 7)) << 3);
        const float* src = (const float*)A + (size_t)r * strideA + k0 + 8 * s;
        float4 fa = *(const float4*)src;
        float4 fb = *(const float4*)(src + 4);
        ushort_t tmp[8] = {f2b(fa.x), f2b(fa.y), f2b(fa.z), f2b(fa.w),
                           f2b(fb.x), f2b(fb.y), f2b(fb.z), f2b(fb.w)};
        *(uint4*)&As[dst] = *(const uint4*)tmp;
      }
    } else {
      // async A: 16 chunks of 64x16B; wave w issues chunks 2w, 2w+1
      #pragma unroll
      for (int rep = 0; rep < 2; ++rep) {
        int chunk = w * 2 + rep;
        int si = chunk * 64 + lane;
        int r = si >> 3, s = si & 7;
        const ushort_t* src =
            (const ushort_t*)A + (size_t)r * strideA + k0 + 8 * (s ^ (r & 7));
        gload16(src, As + chunk * 512);
      }
    }
    // async B: 32 chunks; wave w issues chunks 4w..4w+3
    #pragma unroll
    for (int rep = 0; rep < 4; ++rep) {
      int chunk = w * 4 + rep;
      int si = chunk * 64 + lane;
      int r = si >> 3, s = si & 7;
      const ushort_t* src = WT + (size_t)r * strideB + k0 + 8 * (s ^ (r & 7));
      gload16(src, Bs + chunk * 512);
    }
    __syncthreads();  // drains vmcnt (global_load_lds) + lgkmcnt (ds_write)
    #pragma unroll
    for (int kk = 0; kk < 2; ++kk) {
      bf16x8 af[4], bfr[4];
      const int s = 4 * kk + q;
      #pragma unroll
      for (int m = 0; m < 4; ++m) {
        int r = wr * 64 + 16 * m + lr;
        af[m] = *(const bf16x8*)&As[r * 64 + ((s ^ (r & 7)) << 3)];
      }
      #pragma unroll
      for (int nn = 0; nn < 4; ++nn) {
        int c = wc * 64 + 16 * nn + lr;
        bfr[nn] = *(const bf16x8*)&Bs[c * 64 + ((s ^ (c & 7)) << 3)];
      }
      #pragma unroll
      for (int m = 0; m < 4; ++m)
        #pragma unroll
        for (int nn = 0; nn < 4; ++nn)
          acc[m][nn] = __builtin_amdgcn_mfma_f32_16x16x32_bf16(
              af[m], bfr[nn], acc[m][nn], 0, 0, 0);
    }
  }
}

__device__ __forceinline__ void zero_acc(f32x4 acc[4][4]) {
  #pragma unroll
  for (int m = 0; m < 4; ++m)
    #pragma unroll
    for (int n = 0; n < 4; ++n) acc[m][n] = 0.0f;
}

// bf16 epilogue store (optional phi) for the 128x256 tile
__device__ __forceinline__ void store_bf16(f32x4 acc[4][4], ushort_t* out,
                                           int row0, int do_phi) {
  const int t = threadIdx.x;
  const int lane = t & 63, w = t >> 6, wr = w >> 2, wc = w & 3;
  const int q = lane >> 4, lr = lane & 15;
  #pragma unroll
  for (int m = 0; m < 4; ++m)
    #pragma unroll
    for (int nn = 0; nn < 4; ++nn) {
      int col = wc * 64 + 16 * nn + lr;
      #pragma unroll
      for (int reg = 0; reg < 4; ++reg) {
        int row = row0 + wr * 64 + 16 * m + 4 * q + reg;
        float v = acc[m][nn][reg];
        if (do_phi) v = (v > 0.f) ? v + 1.f : __expf(v);
        out[(size_t)row * 256 + col] = f2b(v);
      }
    }
}

// ---------------------------------------------------------------------------
// x (fp32) -> xb (bf16), vectorized: 8 elems/thread.
// ---------------------------------------------------------------------------
__global__ __launch_bounds__(256) void xconv_kernel(const float* __restrict__ x,
                                                    ushort_t* __restrict__ xb) {
  size_t i = ((size_t)blockIdx.x * 256 + threadIdx.x) * 8;
  float4 a = *(const float4*)&x[i];
  float4 b = *(const float4*)&x[i + 4];
  ushort_t tmp[8] = {f2b(a.x), f2b(a.y), f2b(a.z), f2b(a.w),
                     f2b(b.x), f2b(b.y), f2b(b.z), f2b(b.w)};
  *(uint4*)&xb[i] = *(const uint4*)tmp;
}

// ---------------------------------------------------------------------------
// Fused QKV from bf16 xb: Q -> Qb (phi), K -> Kb (phi), V -> OVER xb in-place
// (safe: block writes only its own rows, after its k-loop reads of them).
// ---------------------------------------------------------------------------
__global__ __launch_bounds__(512) void qkv3_kernel(
    ushort_t* __restrict__ xb, const ushort_t* __restrict__ WqT,
    const ushort_t* __restrict__ WkT, const ushort_t* __restrict__ WvT,
    ushort_t* __restrict__ Qb, ushort_t* __restrict__ Kb) {
  __shared__ short As[128 * 64];
  __shared__ short Bs[256 * 64];
  const int row0 = blockIdx.x * 128;
  const ushort_t* Ax = xb + (size_t)row0 * 256;
  f32x4 acc[4][4];

  zero_acc(acc);
  gemm_core3<0>(Ax, 256, WqT, 256, As, Bs, acc, 4);
  store_bf16(acc, Qb, row0, 1);
  zero_acc(acc);
  gemm_core3<0>(Ax, 256, WkT, 256, As, Bs, acc, 4);
  store_bf16(acc, Kb, row0, 1);
  zero_acc(acc);
  gemm_core3<0>(Ax, 256, WvT, 256, As, Bs, acc, 4);
  __syncthreads();  // all reads of xb tile done before overwrite
  store_bf16(acc, xb, row0, 0);
}

// ---------------------------------------------------------------------------
// GEMM + LayerNorm. A bf16 panel. RESID=0: out bf16 (m1). RESID=1:
// out = x + LN(...) fp32.
// ---------------------------------------------------------------------------
template <int RESID>
__global__ __launch_bounds__(512) void gemmln2(
    const ushort_t* __restrict__ A, const ushort_t* __restrict__ WT,
    const float* __restrict__ g, const float* __restrict__ bvec,
    const float* __restrict__ resid, void* Out) {
  __shared__ short As[128 * 64];
  __shared__ short Bs[256 * 64];
  __shared__ float p1[128][4], p2[128][4], mus[128], rns[128];
  const int row0 = blockIdx.x * 128;
  f32x4 acc[4][4];
  zero_acc(acc);
  gemm_core3<0>(A + (size_t)row0 * 256, 256, WT, 256, As, Bs, acc, 4);
  const int t = threadIdx.x;
  const int lane = t & 63, w = t >> 6, wr = w >> 2, wc = w & 3;
  const int q = lane >> 4, lr = lane & 15;
  #pragma unroll
  for (int m = 0; m < 4; ++m)
    #pragma unroll
    for (int reg = 0; reg < 4; ++reg) {
      float s1 = 0.f, s2 = 0.f;
      #pragma unroll
      for (int nn = 0; nn < 4; ++nn) {
        float v = acc[m][nn][reg];
        s1 += v;
        s2 += v * v;
      }
      #pragma unroll
      for (int msk = 8; msk >= 1; msk >>= 1) {
        s1 += __shfl_xor(s1, msk);
        s2 += __shfl_xor(s2, msk);
      }
      if (lr == 0) {
        int rl = wr * 64 + 16 * m + 4 * q + reg;
        p1[rl][wc] = s1;
        p2[rl][wc] = s2;
      }
    }
  __syncthreads();
  if (t < 128) {
    float a = 0.f, b = 0.f;
    #pragma unroll
    for (int ww = 0; ww < 4; ++ww) {
      a += p1[t][ww];
      b += p2[t][ww];
    }
    float mu = a * (1.f / 256.f);
    float var = b * (1.f / 256.f) - mu * mu;
    mus[t] = mu;
    rns[t] = rsqrtf(var + 1e-5f);
  }
  __syncthreads();
  #pragma unroll
  for (int m = 0; m < 4; ++m)
    #pragma unroll
    for (int nn = 0; nn < 4; ++nn) {
      int col = wc * 64 + 16 * nn + lr;
      float gv = g[col], bv = bvec[col];
      #pragma unroll
      for (int reg = 0; reg < 4; ++reg) {
        int rl = wr * 64 + 16 * m + 4 * q + reg;
        int row = row0 + rl;
        float v = (acc[m][nn][reg] - mus[rl]) * rns[rl] * gv + bv;
        if (RESID) {
          v += resid[(size_t)row * 256 + col];
          ((float*)Out)[(size_t)row * 256 + col] = v;
        } else {
          ((ushort_t*)Out)[(size_t)row * 256 + col] = f2b(v);
        }
      }
    }
}

// ---------------------------------------------------------------------------
// MLP1: h = relu(x @ W1[:256] + m1 @ W1[256:]) -> bf16. x is fp32 (xb dead).
// ---------------------------------------------------------------------------
__global__ __launch_bounds__(512) void mlp1_v2(const float* __restrict__ x,
                                               const ushort_t* __restrict__ m1,
                                               const ushort_t* __restrict__ W1T,
                                               ushort_t* __restrict__ H) {
  __shared__ short As[128 * 64];
  __shared__ short Bs[256 * 64];
  const int row0 = blockIdx.x * 128;
  f32x4 acc[4][4];
  zero_acc(acc);
  gemm_core3<1>(x + (size_t)row0 * 256, 256, W1T, 512, As, Bs, acc, 4);
  gemm_core3<0>(m1 + (size_t)row0 * 256, 256, W1T + 256, 512, As, Bs, acc, 4);
  const int t = threadIdx.x;
  const int lane = t & 63, w = t >> 6, wr = w >> 2, wc = w & 3;
  const int q = lane >> 4, lr = lane & 15;
  #pragma unroll
  for (int m = 0; m < 4; ++m)
    #pragma unroll
    for (int nn = 0; nn < 4; ++nn) {
      int col = wc * 64 + 16 * nn + lr;
      #pragma unroll
      for (int reg = 0; reg < 4; ++reg) {
        int row = row0 + wr * 64 + 16 * m + 4 * q + reg;
        H[(size_t)row * 256 + col] = f2b(fmaxf(acc[m][nn][reg], 0.f));
      }
    }
}

// ---------------------------------------------------------------------------
// Weight transpose+convert: W[K][N] f32 -> WT[N][K] bf16. grid (N/64, K/64).
// ---------------------------------------------------------------------------
__global__ __launch_bounds__(256) void wtrans_kernel(const float* __restrict__ W,
                                                     ushort_t* __restrict__ WT,
                                                     int K, int N) {
  __shared__ float tile[64][65];
  const int t = threadIdx.x;
  const int bx = blockIdx.x, by = blockIdx.y;
  for (int i = t; i < 4096; i += 256) {
    int r = i >> 6, c = i & 63;
    tile[r][c] = W[(size_t)(by * 64 + r) * N + bx * 64 + c];
  }
  __syncthreads();
  for (int i = t; i < 4096; i += 256) {
    int r = i >> 6, c = i & 63;
    WT[(size_t)(bx * 64 + r) * K + by * 64 + c] = f2b(tile[c][r]);
  }
}

// ---------------------------------------------------------------------------
// KV partial: K,V bf16 full panels. grid = (NB*HB, SPLITS). fp32 math.
// ---------------------------------------------------------------------------
__global__ __launch_bounds__(256) void kv_partial_kernel(
    const ushort_t* __restrict__ K, const ushort_t* __restrict__ V,
    float* __restrict__ Pp) {
  __shared__ float Ksh[64][32];
  __shared__ float Vsh[64][32];
  const int nh = blockIdx.x;
  const int n = nh >> 3, h = nh & 7;
  const int l0 = n * LB + blockIdx.y * SPLIT_ROWS;
  const int t = threadIdx.x;
  const int d = t >> 3, vg = t & 7;
  float acc[4] = {0.f, 0.f, 0.f, 0.f};
  float ksacc = 0.f;
  for (int tile = 0; tile < SPLIT_ROWS / 64; ++tile) {
    __syncthreads();
    {
      int rr = t >> 2, c8 = t & 3;
      size_t base = (size_t)(l0 + tile * 64 + rr) * 256 + h * 32 + 8 * c8;
      uint4 kr = *(const uint4*)&K[base];
      uint4 vr = *(const uint4*)&V[base];
      const ushort_t* kp = (const ushort_t*)&kr;
      const ushort_t* vp = (const ushort_t*)&vr;
      #pragma unroll
      for (int e = 0; e < 8; ++e) {
        Ksh[rr][8 * c8 + e] = b2f(kp[e]);
        Vsh[rr][8 * c8 + e] = b2f(vp[e]);
      }
    }
    __syncthreads();
    for (int r = 0; r < 64; ++r) {
      float kv = Ksh[r][d];
      if (vg == 0) ksacc += kv;
      #pragma unroll
      for (int qq = 0; qq < 4; ++qq)
        acc[qq] = fmaf(kv, Vsh[r][vg * 4 + qq], acc[qq]);
    }
  }
  float* rec = Pp + (size_t)(blockIdx.y * (NB * HB) + nh) * 1056;
  #pragma unroll
  for (int qq = 0; qq < 4; ++qq) rec[d * 32 + vg * 4 + qq] = acc[qq];
  if (vg == 0) rec[1024 + d] = ksacc;
}

__global__ __launch_bounds__(256) void kv_final_kernel(
    const float* __restrict__ Pp, float* __restrict__ KV,
    float* __restrict__ KS) {
  const int nh = blockIdx.x;
  const int t = threadIdx.x;
  for (int i = t; i < 1056; i += 256) {
    float s = 0.f;
    for (int sp = 0; sp < SPLITS; ++sp)
      s += Pp[(size_t)(sp * (NB * HB) + nh) * 1056 + i];
    if (i < 1024)
      KV[(size_t)nh * 1024 + i] = s;
    else
      KS[nh * 32 + (i - 1024)] = s;
  }
}

// ---------------------------------------------------------------------------
// msg in-place on bf16 Q panel: msg = (Q.KV)/(Q.Ksum+eps); /L and *L cancel.
// ---------------------------------------------------------------------------
__global__ __launch_bounds__(256) void msg_kernel(ushort_t* __restrict__ QM,
                                                  const float* __restrict__ KV,
                                                  const float* __restrict__ KS) {
  __shared__ float Qs[32][256];
  __shared__ float kvs[8][32][32];
  __shared__ float ks[8][32];
  __shared__ float zs[32][8];
  const int t = threadIdx.x;
  const int row0 = blockIdx.x * 32;
  const int n = row0 >> 14;  // L = 16384
  #pragma unroll
  for (int j = 0; j < 4; ++j) {
    int fi = t + 256 * j;
    int rr = fi >> 5, g8 = fi & 31;
    uint4 raw = *(const uint4*)&QM[(size_t)(row0 + rr) * 256 + 8 * g8];
    const ushort_t* pr = (const ushort_t*)&raw;
    #pragma unroll
    for (int e = 0; e < 8; ++e) Qs[rr][8 * g8 + e] = b2f(pr[e]);
  }
  const float* KVn = KV + (size_t)n * (HB * DB * DB);
  #pragma unroll
  for (int r = 0; r < 8; ++r) {
    int fi = t + 256 * r;
    ((float4*)kvs)[fi] = ((const float4*)KVn)[fi];
  }
  ((float*)ks)[t] = KS[n * 256 + t];
  __syncthreads();
  {
    int l = t >> 3, h = t & 7;
    float dsum = 0.f;
    #pragma unroll
    for (int dd = 0; dd < 32; ++dd)
      dsum = fmaf(Qs[l][h * 32 + dd], ks[h][dd], dsum);
    zs[l][h] = 1.0f / (dsum + 1e-6f);
  }
  __syncthreads();
  const int c = t, h = c >> 5, v = c & 31;
  for (int l = 0; l < 32; ++l) {
    float s = 0.f;
    #pragma unroll
    for (int dd = 0; dd < 32; ++dd)
      s = fmaf(Qs[l][h * 32 + dd], kvs[h][dd][v], s);
    QM[(size_t)(row0 + l) * 256 + c] = f2b(s * zs[l][h]);
  }
}

// ---------------------------------------------------------------------------
// Buffers (ws ~38.6 MB, identical budget to proven rounds 3-5):
//   ws slot (32 MiB): xb -> V (in-place) -> H
//   d_out lo: Q -> msg -> final out (lo) ; d_out hi: K -> m1 -> final out (hi)
// Every word written before read; no atomics/memsets.
// ---------------------------------------------------------------------------
extern "C" void kernel_launch(void* const* d_in, const int* in_sizes, int n_in,
                              void* d_out, int out_size, void* d_ws,
                              size_t ws_size, hipStream_t stream) {
  const float* x = (const float*)d_in[0];
  const float* Wq = (const float*)d_in[1];
  const float* Wk = (const float*)d_in[2];
  const float* Wv = (const float*)d_in[3];
  const float* Wm = (const float*)d_in[4];
  const float* W1 = (const float*)d_in[5];
  const float* W2 = (const float*)d_in[6];
  const float* g1 = (const float*)d_in[7];
  const float* b1 = (const float*)d_in[8];
  const float* g2 = (const float*)d_in[9];
  const float* b2 = (const float*)d_in[10];
  float* out = (float*)d_out;

  const size_t PE = (size_t)NLB * CB;  // 16.7M elems
  ushort_t* Qb = (ushort_t*)d_out;                    // lower 32 MiB
  ushort_t* Kb = (ushort_t*)((char*)d_out + PE * 2);  // upper 32 MiB

  char* wsb = (char*)d_ws;
  ushort_t* Vxb = (ushort_t*)wsb;  // 32 MiB: xb -> V -> H
  float* Pp = (float*)(wsb + PE * 2);                 // 4.3 MB
  float* KVb = Pp + (size_t)SPLITS * NB * HB * 1056;  // 128 KB
  float* KSb = KVb + (size_t)NB * HB * DB * DB;       // 4 KB
  ushort_t* WqT = (ushort_t*)(KSb + NB * HB * DB);
  ushort_t* WkT = WqT + 256 * 256;
  ushort_t* WvT = WkT + 256 * 256;
  ushort_t* WmT = WvT + 256 * 256;
  ushort_t* W2T = WmT + 256 * 256;
  ushort_t* W1T = W2T + 256 * 256;  // [256][512]

  wtrans_kernel<<<dim3(4, 4), 256, 0, stream>>>(Wq, WqT, 256, 256);
  wtrans_kernel<<<dim3(4, 4), 256, 0, stream>>>(Wk, WkT, 256, 256);
  wtrans_kernel<<<dim3(4, 4), 256, 0, stream>>>(Wv, WvT, 256, 256);
  wtrans_kernel<<<dim3(4, 4), 256, 0, stream>>>(Wm, WmT, 256, 256);
  wtrans_kernel<<<dim3(4, 4), 256, 0, stream>>>(W2, W2T, 256, 256);
  wtrans_kernel<<<dim3(4, 8), 256, 0, stream>>>(W1, W1T, 512, 256);

  // x -> bf16 once; all GEMM A-panels become async-stageable
  xconv_kernel<<<PE / 2048, 256, 0, stream>>>(x, Vxb);
  // Q,K -> d_out; V overwrites xb in-place
  qkv3_kernel<<<NLB / 128, 512, 0, stream>>>(Vxb, WqT, WkT, WvT, Qb, Kb);
  kv_partial_kernel<<<dim3(NB * HB, SPLITS), 256, 0, stream>>>(Kb, Vxb, Pp);
  kv_final_kernel<<<NB * HB, 256, 0, stream>>>(Pp, KVb, KSb);
  msg_kernel<<<NLB / 32, 256, 0, stream>>>(Qb, KVb, KSb);
  // m1 = LN(msg @ Wm) -> Kb slot (K dead)
  gemmln2<0><<<NLB / 128, 512, 0, stream>>>(Qb, WmT, g1, b1, nullptr, Kb);
  // h = relu(x@W1a + m1@W1b) -> ws slot (V dead)
  mlp1_v2<<<NLB / 128, 512, 0, stream>>>(x, Kb, W1T, Vxb);
  // out = x + LN(h @ W2) -> full d_out (msg/m1 dead)
  gemmln2<1><<<NLB / 128, 512, 0, stream>>>(Vxb, W2T, g2, b2, x, out);
}

// Round 7
// 366.074 us; speedup vs baseline: 1.0795x; 1.0795x over previous
//
#include <hip/hip_runtime.h>
#include <hip/hip_bf16.h>
#include <math.h>

#define NB 4
#define LB 16384
#define CB 256
#define HB 8
#define DB 32
#define NLB (NB * LB)
#define SPLITS 32
#define SPLIT_ROWS (LB / SPLITS)  // 512

typedef unsigned short ushort_t;
typedef __attribute__((ext_vector_type(8))) short bf16x8;
typedef __attribute__((ext_vector_type(4))) float f32x4;

__device__ __forceinline__ ushort_t f2b(float f) {
  union { __hip_bfloat16 h; ushort_t u; } cv;
  cv.h = __float2bfloat16(f);
  return cv.u;
}
__device__ __forceinline__ float b2f(ushort_t u) {
  union { __hip_bfloat16 h; ushort_t u; } cv;
  cv.u = u;
  return __bfloat162float(cv.h);
}

__device__ __forceinline__ void gload16(const void* g, void* l) {
  __builtin_amdgcn_global_load_lds(
      (const __attribute__((address_space(1))) void*)g,
      (__attribute__((address_space(3))) void*)l, 16, 0, 0);
}

// ---------------------------------------------------------------------------
// MFMA GEMM core (round-6 verified: SQ_LDS_BANK_CONFLICT = 0):
// 128x256 tile, 512 threads (8 waves: wr=w>>2, wc=w&3), BK=64. B (and A when
// bf16) staged via width-16 global_load_lds into LINEAR LDS with INVERSE-
// swizzled global source (rule #21). AF32 path reg-stages with f32->bf16.
// Fragments: A lane lr=row, q=k-slot; B lane lr=col, q=k-slot; C row=4q+reg,
// col=lr.
// ---------------------------------------------------------------------------
template <int AF32>
__device__ __forceinline__ void gemm_core3(const void* A, int strideA,
                                           const ushort_t* __restrict__ WT,
                                           int strideB, short* As, short* Bs,
                                           f32x4 acc[4][4], int nk) {
  const int t = threadIdx.x;
  const int lane = t & 63;
  const int w = t >> 6, wr = w >> 2, wc = w & 3;
  const int q = lane >> 4, lr = lane & 15;
  for (int ks = 0; ks < nk; ++ks) {
    const int k0 = ks * 64;
    __syncthreads();
    if (AF32) {
      #pragma unroll
      for (int rep = 0; rep < 2; ++rep) {
        int si = t + 512 * rep;
        int r = si >> 3, s = si & 7;
        int dst = r * 64 + ((s ^ (r & 7)) << 3);
        const float* src = (const float*)A + (size_t)r * strideA + k0 + 8 * s;
        float4 fa = *(const float4*)src;
        float4 fb = *(const float4*)(src + 4);
        ushort_t tmp[8] = {f2b(fa.x), f2b(fa.y), f2b(fa.z), f2b(fa.w),
                           f2b(fb.x), f2b(fb.y), f2b(fb.z), f2b(fb.w)};
        *(uint4*)&As[dst] = *(const uint4*)tmp;
      }
    } else {
      #pragma unroll
      for (int rep = 0; rep < 2; ++rep) {
        int chunk = w * 2 + rep;
        int si = chunk * 64 + lane;
        int r = si >> 3, s = si & 7;
        const ushort_t* src =
            (const ushort_t*)A + (size_t)r * strideA + k0 + 8 * (s ^ (r & 7));
        gload16(src, As + chunk * 512);
      }
    }
    #pragma unroll
    for (int rep = 0; rep < 4; ++rep) {
      int chunk = w * 4 + rep;
      int si = chunk * 64 + lane;
      int r = si >> 3, s = si & 7;
      const ushort_t* src = WT + (size_t)r * strideB + k0 + 8 * (s ^ (r & 7));
      gload16(src, Bs + chunk * 512);
    }
    __syncthreads();  // drains vmcnt (global_load_lds) + lgkmcnt (ds_write)
    #pragma unroll
    for (int kk = 0; kk < 2; ++kk) {
      bf16x8 af[4], bfr[4];
      const int s = 4 * kk + q;
      #pragma unroll
      for (int m = 0; m < 4; ++m) {
        int r = wr * 64 + 16 * m + lr;
        af[m] = *(const bf16x8*)&As[r * 64 + ((s ^ (r & 7)) << 3)];
      }
      #pragma unroll
      for (int nn = 0; nn < 4; ++nn) {
        int c = wc * 64 + 16 * nn + lr;
        bfr[nn] = *(const bf16x8*)&Bs[c * 64 + ((s ^ (c & 7)) << 3)];
      }
      #pragma unroll
      for (int m = 0; m < 4; ++m)
        #pragma unroll
        for (int nn = 0; nn < 4; ++nn)
          acc[m][nn] = __builtin_amdgcn_mfma_f32_16x16x32_bf16(
              af[m], bfr[nn], acc[m][nn], 0, 0, 0);
    }
  }
}

__device__ __forceinline__ void zero_acc(f32x4 acc[4][4]) {
  #pragma unroll
  for (int m = 0; m < 4; ++m)
    #pragma unroll
    for (int n = 0; n < 4; ++n) acc[m][n] = 0.0f;
}

__device__ __forceinline__ void store_bf16(f32x4 acc[4][4], ushort_t* out,
                                           int row0, int do_phi) {
  const int t = threadIdx.x;
  const int lane = t & 63, w = t >> 6, wr = w >> 2, wc = w & 3;
  const int q = lane >> 4, lr = lane & 15;
  #pragma unroll
  for (int m = 0; m < 4; ++m)
    #pragma unroll
    for (int nn = 0; nn < 4; ++nn) {
      int col = wc * 64 + 16 * nn + lr;
      #pragma unroll
      for (int reg = 0; reg < 4; ++reg) {
        int row = row0 + wr * 64 + 16 * m + 4 * q + reg;
        float v = acc[m][nn][reg];
        if (do_phi) v = (v > 0.f) ? v + 1.f : __expf(v);
        out[(size_t)row * 256 + col] = f2b(v);
      }
    }
}

// ---------------------------------------------------------------------------
// x (fp32) -> xb (bf16), vectorized: 8 elems/thread.
// ---------------------------------------------------------------------------
__global__ __launch_bounds__(256) void xconv_kernel(const float* __restrict__ x,
                                                    ushort_t* __restrict__ xb) {
  size_t i = ((size_t)blockIdx.x * 256 + threadIdx.x) * 8;
  float4 a = *(const float4*)&x[i];
  float4 b = *(const float4*)&x[i + 4];
  ushort_t tmp[8] = {f2b(a.x), f2b(a.y), f2b(a.z), f2b(a.w),
                     f2b(b.x), f2b(b.y), f2b(b.z), f2b(b.w)};
  *(uint4*)&xb[i] = *(const uint4*)tmp;
}

// ---------------------------------------------------------------------------
// Fused QKV from bf16 xb: Q -> Qb (phi), K -> Kb (phi), V -> OVER xb in-place.
// ---------------------------------------------------------------------------
__global__ __launch_bounds__(512) void qkv3_kernel(
    ushort_t* __restrict__ xb, const ushort_t* __restrict__ WqT,
    const ushort_t* __restrict__ WkT, const ushort_t* __restrict__ WvT,
    ushort_t* __restrict__ Qb, ushort_t* __restrict__ Kb) {
  __shared__ short As[128 * 64];
  __shared__ short Bs[256 * 64];
  const int row0 = blockIdx.x * 128;
  const ushort_t* Ax = xb + (size_t)row0 * 256;
  f32x4 acc[4][4];

  zero_acc(acc);
  gemm_core3<0>(Ax, 256, WqT, 256, As, Bs, acc, 4);
  store_bf16(acc, Qb, row0, 1);
  zero_acc(acc);
  gemm_core3<0>(Ax, 256, WkT, 256, As, Bs, acc, 4);
  store_bf16(acc, Kb, row0, 1);
  zero_acc(acc);
  gemm_core3<0>(Ax, 256, WvT, 256, As, Bs, acc, 4);
  __syncthreads();  // all reads of xb tile done before overwrite
  store_bf16(acc, xb, row0, 0);
}

// ---------------------------------------------------------------------------
// GEMM + LayerNorm. A bf16 panel. RESID=0: B = MT[n] (per-batch folded
// attention matrix), out bf16 (m1). RESID=1: B = W2T, out = x + LN(...) fp32.
// ---------------------------------------------------------------------------
template <int RESID>
__global__ __launch_bounds__(512) void gemmln2(
    const ushort_t* __restrict__ A, const ushort_t* __restrict__ WT,
    const float* __restrict__ g, const float* __restrict__ bvec,
    const float* __restrict__ resid, void* Out) {
  __shared__ short As[128 * 64];
  __shared__ short Bs[256 * 64];
  __shared__ float p1[128][4], p2[128][4], mus[128], rns[128];
  const int row0 = blockIdx.x * 128;
  const ushort_t* WTn = RESID ? WT : WT + (size_t)(row0 >> 14) * 65536;
  f32x4 acc[4][4];
  zero_acc(acc);
  gemm_core3<0>(A + (size_t)row0 * 256, 256, WTn, 256, As, Bs, acc, 4);
  const int t = threadIdx.x;
  const int lane = t & 63, w = t >> 6, wr = w >> 2, wc = w & 3;
  const int q = lane >> 4, lr = lane & 15;
  #pragma unroll
  for (int m = 0; m < 4; ++m)
    #pragma unroll
    for (int reg = 0; reg < 4; ++reg) {
      float s1 = 0.f, s2 = 0.f;
      #pragma unroll
      for (int nn = 0; nn < 4; ++nn) {
        float v = acc[m][nn][reg];
        s1 += v;
        s2 += v * v;
      }
      #pragma unroll
      for (int msk = 8; msk >= 1; msk >>= 1) {
        s1 += __shfl_xor(s1, msk);
        s2 += __shfl_xor(s2, msk);
      }
      if (lr == 0) {
        int rl = wr * 64 + 16 * m + 4 * q + reg;
        p1[rl][wc] = s1;
        p2[rl][wc] = s2;
      }
    }
  __syncthreads();
  if (t < 128) {
    float a = 0.f, b = 0.f;
    #pragma unroll
    for (int ww = 0; ww < 4; ++ww) {
      a += p1[t][ww];
      b += p2[t][ww];
    }
    float mu = a * (1.f / 256.f);
    float var = b * (1.f / 256.f) - mu * mu;
    mus[t] = mu;
    rns[t] = rsqrtf(var + 1e-5f);
  }
  __syncthreads();
  #pragma unroll
  for (int m = 0; m < 4; ++m)
    #pragma unroll
    for (int nn = 0; nn < 4; ++nn) {
      int col = wc * 64 + 16 * nn + lr;
      float gv = g[col], bv = bvec[col];
      #pragma unroll
      for (int reg = 0; reg < 4; ++reg) {
        int rl = wr * 64 + 16 * m + 4 * q + reg;
        int row = row0 + rl;
        float v = (acc[m][nn][reg] - mus[rl]) * rns[rl] * gv + bv;
        if (RESID) {
          v += resid[(size_t)row * 256 + col];
          ((float*)Out)[(size_t)row * 256 + col] = v;
        } else {
          ((ushort_t*)Out)[(size_t)row * 256 + col] = f2b(v);
        }
      }
    }
}

// ---------------------------------------------------------------------------
// MLP1: h = relu(x @ W1[:256] + m1 @ W1[256:]) -> bf16. x fp32 (xb dead).
// ---------------------------------------------------------------------------
__global__ __launch_bounds__(512) void mlp1_v2(const float* __restrict__ x,
                                               const ushort_t* __restrict__ m1,
                                               const ushort_t* __restrict__ W1T,
                                               ushort_t* __restrict__ H) {
  __shared__ short As[128 * 64];
  __shared__ short Bs[256 * 64];
  const int row0 = blockIdx.x * 128;
  f32x4 acc[4][4];
  zero_acc(acc);
  gemm_core3<1>(x + (size_t)row0 * 256, 256, W1T, 512, As, Bs, acc, 4);
  gemm_core3<0>(m1 + (size_t)row0 * 256, 256, W1T + 256, 512, As, Bs, acc, 4);
  const int t = threadIdx.x;
  const int lane = t & 63, w = t >> 6, wr = w >> 2, wc = w & 3;
  const int q = lane >> 4, lr = lane & 15;
  #pragma unroll
  for (int m = 0; m < 4; ++m)
    #pragma unroll
    for (int nn = 0; nn < 4; ++nn) {
      int col = wc * 64 + 16 * nn + lr;
      #pragma unroll
      for (int reg = 0; reg < 4; ++reg) {
        int row = row0 + wr * 64 + 16 * m + 4 * q + reg;
        H[(size_t)row * 256 + col] = f2b(fmaxf(acc[m][nn][reg], 0.f));
      }
    }
}

// ---------------------------------------------------------------------------
// All weight transposes in ONE launch. grid (4, 8, 5); z: 0=Wq 1=Wk 2=Wv
// 3=W2 (K=256, by<4), 4=W1 (K=512). W[K][256] f32 -> WT[256][K] bf16.
// ---------------------------------------------------------------------------
__global__ __launch_bounds__(256) void wtrans_all(
    const float* __restrict__ Wq, const float* __restrict__ Wk,
    const float* __restrict__ Wv, const float* __restrict__ W2,
    const float* __restrict__ W1, ushort_t* __restrict__ WqT,
    ushort_t* __restrict__ WkT, ushort_t* __restrict__ WvT,
    ushort_t* __restrict__ W2T, ushort_t* __restrict__ W1T) {
  const int z = blockIdx.z;
  const float* W;
  ushort_t* WT;
  int K = 256;
  switch (z) {
    case 0: W = Wq; WT = WqT; break;
    case 1: W = Wk; WT = WkT; break;
    case 2: W = Wv; WT = WvT; break;
    case 3: W = W2; WT = W2T; break;
    default: W = W1; WT = W1T; K = 512; break;
  }
  const int by = blockIdx.y;
  if (by * 64 >= K) return;
  __shared__ float tile[64][65];
  const int t = threadIdx.x;
  const int bx = blockIdx.x;
  for (int i = t; i < 4096; i += 256) {
    int r = i >> 6, c = i & 63;
    tile[r][c] = W[(size_t)(by * 64 + r) * 256 + bx * 64 + c];
  }
  __syncthreads();
  for (int i = t; i < 4096; i += 256) {
    int r = i >> 6, c = i & 63;
    WT[(size_t)(bx * 64 + r) * K + by * 64 + c] = f2b(tile[c][r]);
  }
}

// ---------------------------------------------------------------------------
// KV partial: K,V bf16 full panels. grid = (NB*HB, SPLITS). fp32 math.
// ---------------------------------------------------------------------------
__global__ __launch_bounds__(256) void kv_partial_kernel(
    const ushort_t* __restrict__ K, const ushort_t* __restrict__ V,
    float* __restrict__ Pp) {
  __shared__ float Ksh[64][32];
  __shared__ float Vsh[64][32];
  const int nh = blockIdx.x;
  const int n = nh >> 3, h = nh & 7;
  const int l0 = n * LB + blockIdx.y * SPLIT_ROWS;
  const int t = threadIdx.x;
  const int d = t >> 3, vg = t & 7;
  float acc[4] = {0.f, 0.f, 0.f, 0.f};
  float ksacc = 0.f;
  for (int tile = 0; tile < SPLIT_ROWS / 64; ++tile) {
    __syncthreads();
    {
      int rr = t >> 2, c8 = t & 3;
      size_t base = (size_t)(l0 + tile * 64 + rr) * 256 + h * 32 + 8 * c8;
      uint4 kr = *(const uint4*)&K[base];
      uint4 vr = *(const uint4*)&V[base];
      const ushort_t* kp = (const ushort_t*)&kr;
      const ushort_t* vp = (const ushort_t*)&vr;
      #pragma unroll
      for (int e = 0; e < 8; ++e) {
        Ksh[rr][8 * c8 + e] = b2f(kp[e]);
        Vsh[rr][8 * c8 + e] = b2f(vp[e]);
      }
    }
    __syncthreads();
    for (int r = 0; r < 64; ++r) {
      float kv = Ksh[r][d];
      if (vg == 0) ksacc += kv;
      #pragma unroll
      for (int qq = 0; qq < 4; ++qq)
        acc[qq] = fmaf(kv, Vsh[r][vg * 4 + qq], acc[qq]);
    }
  }
  float* rec = Pp + (size_t)(blockIdx.y * (NB * HB) + nh) * 1056;
  #pragma unroll
  for (int qq = 0; qq < 4; ++qq) rec[d * 32 + vg * 4 + qq] = acc[qq];
  if (vg == 0) rec[1024 + d] = ksacc;
}

// ---------------------------------------------------------------------------
// kv_final + fold Wm: sums partials -> KV_h (LDS), KS (global fp32), then
// M_h = KV_h @ Wm_h  ->  MT[n][c][32h+d] bf16 (B-operand layout for gemmln).
// grid = NB*HB, 256 threads (thread = output column c).
// ---------------------------------------------------------------------------
__global__ __launch_bounds__(256) void kv_finalM_kernel(
    const float* __restrict__ Pp, const float* __restrict__ Wm,
    ushort_t* __restrict__ MT, float* __restrict__ KS) {
  const int nh = blockIdx.x;
  const int n = nh >> 3, h = nh & 7;
  const int t = threadIdx.x;
  __shared__ float kvs[1024];  // KV_h[d][v]
  for (int i = t; i < 1056; i += 256) {
    float s = 0.f;
    for (int sp = 0; sp < SPLITS; ++sp)
      s += Pp[(size_t)(sp * (NB * HB) + nh) * 1056 + i];
    if (i < 1024)
      kvs[i] = s;
    else
      KS[n * 256 + h * 32 + (i - 1024)] = s;
  }
  __syncthreads();
  // wmv[v] = Wm[32h+v][c=t]  (coalesced per v)
  float wmv[32];
  #pragma unroll
  for (int v = 0; v < 32; ++v) wmv[v] = Wm[(size_t)(32 * h + v) * 256 + t];
  ushort_t mrow[32];
  #pragma unroll
  for (int d = 0; d < 32; ++d) {
    float s = 0.f;
    #pragma unroll
    for (int v = 0; v < 32; ++v) s = fmaf(kvs[d * 32 + v], wmv[v], s);
    mrow[d] = f2b(s);
  }
  ushort_t* dst = MT + (size_t)n * 65536 + (size_t)t * 256 + 32 * h;
  #pragma unroll
  for (int j = 0; j < 4; ++j)
    *(uint4*)&dst[8 * j] = *(const uint4*)&mrow[8 * j];
}

// ---------------------------------------------------------------------------
// z-scale: Q[l, 32h..32h+31] *= 1/(Q_h . KS_h + eps), in place on bf16 Q.
// Block = 256 thr = 32 rows x 8 heads; 32-row blocks never straddle n.
// ---------------------------------------------------------------------------
__global__ __launch_bounds__(256) void zscale_kernel(ushort_t* __restrict__ Q,
                                                     const float* __restrict__ KS) {
  __shared__ float ks[256];
  const int t = threadIdx.x;
  const int row0 = blockIdx.x * 32;
  const int n = row0 >> 14;
  ks[t] = KS[(n << 8) + t];
  __syncthreads();
  const int r = t >> 3, h = t & 7;
  ushort_t* p = Q + (size_t)(row0 + r) * 256 + 32 * h;
  uint4 raw[4];
  #pragma unroll
  for (int j = 0; j < 4; ++j) raw[j] = *(const uint4*)&p[8 * j];
  const ushort_t* q16 = (const ushort_t*)raw;
  float dot = 0.f;
  #pragma unroll
  for (int d = 0; d < 32; ++d) dot = fmaf(b2f(q16[d]), ks[32 * h + d], dot);
  const float z = 1.0f / (dot + 1e-6f);
  ushort_t outv[32];
  #pragma unroll
  for (int d = 0; d < 32; ++d) outv[d] = f2b(b2f(q16[d]) * z);
  #pragma unroll
  for (int j = 0; j < 4; ++j) *(uint4*)&p[8 * j] = *(const uint4*)&outv[8 * j];
}

// ---------------------------------------------------------------------------
// Buffers (ws ~38 MB, proven budget):
//   ws slot (32 MiB): xb -> V (in-place) -> H
//   d_out lo: Q -> Q' (z-scaled) -> final out; d_out hi: K -> m1 -> final out
//   MT 512 KB, KS 4 KB, Pp 4.3 MB, weight transposes ~768 KB.
// Every word written before read; no atomics/memsets.
// ---------------------------------------------------------------------------
extern "C" void kernel_launch(void* const* d_in, const int* in_sizes, int n_in,
                              void* d_out, int out_size, void* d_ws,
                              size_t ws_size, hipStream_t stream) {
  const float* x = (const float*)d_in[0];
  const float* Wq = (const float*)d_in[1];
  const float* Wk = (const float*)d_in[2];
  const float* Wv = (const float*)d_in[3];
  const float* Wm = (const float*)d_in[4];
  const float* W1 = (const float*)d_in[5];
  const float* W2 = (const float*)d_in[6];
  const float* g1 = (const float*)d_in[7];
  const float* b1 = (const float*)d_in[8];
  const float* g2 = (const float*)d_in[9];
  const float* b2 = (const float*)d_in[10];
  float* out = (float*)d_out;

  const size_t PE = (size_t)NLB * CB;  // 16.7M elems
  ushort_t* Qb = (ushort_t*)d_out;                    // lower 32 MiB
  ushort_t* Kb = (ushort_t*)((char*)d_out + PE * 2);  // upper 32 MiB

  char* wsb = (char*)d_ws;
  ushort_t* Vxb = (ushort_t*)wsb;  // 32 MiB: xb -> V -> H
  float* Pp = (float*)(wsb + PE * 2);                 // 4.3 MB
  float* KSb = Pp + (size_t)SPLITS * NB * HB * 1056;  // 4 KB  [n][h][32]
  ushort_t* MT = (ushort_t*)(KSb + NB * HB * DB);     // 512 KB [n][c][k]
  ushort_t* WqT = MT + (size_t)NB * 256 * 256;
  ushort_t* WkT = WqT + 256 * 256;
  ushort_t* WvT = WkT + 256 * 256;
  ushort_t* W2T = WvT + 256 * 256;
  ushort_t* W1T = W2T + 256 * 256;  // [256][512]

  wtrans_all<<<dim3(4, 8, 5), 256, 0, stream>>>(Wq, Wk, Wv, W2, W1, WqT, WkT,
                                                WvT, W2T, W1T);
  // x -> bf16 once
  xconv_kernel<<<PE / 2048, 256, 0, stream>>>(x, Vxb);
  // Q,K -> d_out; V overwrites xb in-place
  qkv3_kernel<<<NLB / 128, 512, 0, stream>>>(Vxb, WqT, WkT, WvT, Qb, Kb);
  kv_partial_kernel<<<dim3(NB * HB, SPLITS), 256, 0, stream>>>(Kb, Vxb, Pp);
  kv_finalM_kernel<<<NB * HB, 256, 0, stream>>>(Pp, Wm, MT, KSb);
  // Q' = z .* Q in place (replaces the entire msg pass)
  zscale_kernel<<<NLB / 32, 256, 0, stream>>>(Qb, KSb);
  // m1 = LN(Q' @ M[n]) -> Kb slot (K dead)
  gemmln2<0><<<NLB / 128, 512, 0, stream>>>(Qb, MT, g1, b1, nullptr, Kb);
  // h = relu(x@W1a + m1@W1b) -> ws slot (V dead)
  mlp1_v2<<<NLB / 128, 512, 0, stream>>>(x, Kb, W1T, Vxb);
  // out = x + LN(h @ W2) -> full d_out (Q'/m1 dead)
  gemmln2<1><<<NLB / 128, 512, 0, stream>>>(Vxb, W2T, g2, b2, x, out);
}